// Round 8
// baseline (1444.340 us; speedup 1.0000x reference)
//
#include <hip/hip_runtime.h>

#define BT 8
#define S 576
#define NL 25
#define D 2048
#define CT 1024
#define BS (BT * S)            // 4608
#define NZ 8                   // 7 LN'd layers + 1 raw (vin path)
#define SCALE 0.03125f         // CT^-0.5
#define LN_EPS 1e-5f
#define COS_EPS 1e-8f

#define LN_BLOCKS (BS * 7)     // 32256
#define WP_BLOCKS (2048 * 9)   // 18432 (64 k-blk x 32 n-blk x 9 weight slabs)

// bf16 MFMA fragment = 8 x 16-bit held as short vector (guide §3 verified form)
typedef __attribute__((ext_vector_type(8))) short bf16x8;
typedef __attribute__((ext_vector_type(4))) float f32x4;

// ---------- helpers ----------

__device__ __forceinline__ unsigned short f2bf(float f) {
  unsigned int u = __float_as_uint(f);
  u += 0x7fffu + ((u >> 16) & 1u);   // round-to-nearest-even
  return (unsigned short)(u >> 16);
}

__device__ __forceinline__ float bf2f(unsigned short h) {
  return __uint_as_float((unsigned int)h << 16);
}

__device__ __forceinline__ void gld_lds16(const void* g, void* l) {
  __builtin_amdgcn_global_load_lds(
      (const __attribute__((address_space(1))) void*)g,
      (__attribute__((address_space(3))) void*)l, 16, 0, 0);
}

__device__ __forceinline__ void store_bf4(unsigned short* out, int idx4, float4 v) {
  union { unsigned short h[4]; uint2 u; } p;
  p.h[0] = f2bf(v.x); p.h[1] = f2bf(v.y); p.h[2] = f2bf(v.z); p.h[3] = f2bf(v.w);
  reinterpret_cast<uint2*>(out)[idx4] = p.u;
}

// ---------- merged prep: LN+gather+convert  AND  weight transpose+convert ----------
// flat grid of LN_BLOCKS + WP_BLOCKS blocks, 256 threads.
// LN part  (bid = j*BS + bs, j<7): LN(features[:,:,24-4j]) -> xa[j] (bf16).
//   j==0 additionally emits the RAW bf16 copy of features[:,:,24] -> xa[7]
//   (vin path) so layer 24 is read from HBM only once.
// WP part  (b2 = bid-LN_BLOCKS = z*2048 + rm): 32x32 transpose tile.
//   z<7 : w_norm layer z [D x CT] -> wT+z*CT*D ([CT][D]);  z==7: w_in likewise;
//   z==8: w_out [CT x CT] -> wOT (k0>=CT guard).
__global__ __launch_bounds__(256) void prep_kernel(
    const float* __restrict__ features, const float* __restrict__ ln_scale,
    const float* __restrict__ ln_bias, const float* __restrict__ w_norm,
    const float* __restrict__ w_in, const float* __restrict__ w_out,
    unsigned short* __restrict__ xa, unsigned short* __restrict__ wT,
    unsigned short* __restrict__ wOT) {
  __shared__ float red[8];
  __shared__ float tile[32][33];
  const int bid = blockIdx.x;
  const int tid = threadIdx.x;

  if (bid < LN_BLOCKS) {
    const int j  = bid / BS;
    const int bs = bid - j * BS;
    const int lay = 24 - 4 * j;                   // LAYER_IDX = 24,20,16,12,8,4,0
    const float4* x = (const float4*)(features + ((size_t)bs * NL + lay) * D);
    unsigned short* out = xa + ((size_t)j * BS + bs) * D;

    float4 v0 = x[tid];
    float4 v1 = x[tid + 256];

    if (j == 0) {  // raw bf16 copy of layer 24 for the vin GEMM input
      unsigned short* raw = xa + ((size_t)7 * BS + bs) * D;
      store_bf4(raw, tid, v0);
      store_bf4(raw, tid + 256, v1);
    }

    float s = v0.x + v0.y + v0.z + v0.w + v1.x + v1.y + v1.z + v1.w;
    float q = v0.x * v0.x + v0.y * v0.y + v0.z * v0.z + v0.w * v0.w +
              v1.x * v1.x + v1.y * v1.y + v1.z * v1.z + v1.w * v1.w;
    #pragma unroll
    for (int o = 32; o; o >>= 1) { s += __shfl_xor(s, o); q += __shfl_xor(q, o); }

    const int w = tid >> 6, l = tid & 63;
    if (l == 0) { red[w] = s; red[4 + w] = q; }
    __syncthreads();
    s = red[0] + red[1] + red[2] + red[3];
    q = red[4] + red[5] + red[6] + red[7];
    const float mu = s * (1.f / (float)D);
    const float var = q * (1.f / (float)D) - mu * mu;
    const float rs = rsqrtf(var + LN_EPS);

    const float4* sc = (const float4*)(ln_scale + (size_t)j * D);
    const float4* bi = (const float4*)(ln_bias + (size_t)j * D);
    float4 s0 = sc[tid], s1 = sc[tid + 256];
    float4 b0 = bi[tid], b1 = bi[tid + 256];
    float4 o0, o1;
    o0.x = (v0.x - mu) * rs * s0.x + b0.x;
    o0.y = (v0.y - mu) * rs * s0.y + b0.y;
    o0.z = (v0.z - mu) * rs * s0.z + b0.z;
    o0.w = (v0.w - mu) * rs * s0.w + b0.w;
    o1.x = (v1.x - mu) * rs * s1.x + b1.x;
    o1.y = (v1.y - mu) * rs * s1.y + b1.y;
    o1.z = (v1.z - mu) * rs * s1.z + b1.z;
    o1.w = (v1.w - mu) * rs * s1.w + b1.w;
    store_bf4(out, tid, o0);
    store_bf4(out, tid + 256, o1);
    return;
  }

  // ---- weight transpose part ----
  const int b2 = bid - LN_BLOCKS;
  const int z  = b2 >> 11;            // /2048
  const int rm = b2 & 2047;
  const int k0 = (rm & 63) * 32;
  const int n0 = (rm >> 6) * 32;
  const float* src;
  unsigned short* dst;
  int K;
  if (z < 7)       { src = w_norm + (size_t)z * D * CT; dst = wT + (size_t)z * CT * D; K = D; }
  else if (z == 7) { src = w_in;                        dst = wT + (size_t)7 * CT * D; K = D; }
  else             { src = w_out;                       dst = wOT;                     K = CT; }
  if (k0 >= K) return;                // z==8 uses only k0<1024
  const int N = CT;

  // read phase: one float4 per thread (8 x 32 map) -> 1 KB/wave coalesced (G13)
  {
    const int q = tid & 7, r = tid >> 3;   // q: 4-col group, r: k-row
    const float4 v = *reinterpret_cast<const float4*>(
        &src[(size_t)(k0 + r) * N + n0 + q * 4]);
    tile[r][q * 4 + 0] = v.x;
    tile[r][q * 4 + 1] = v.y;
    tile[r][q * 4 + 2] = v.z;
    tile[r][q * 4 + 3] = v.w;
  }
  __syncthreads();
  const int tx = tid & 31, ty = tid >> 5;   // 32 x 8
  #pragma unroll
  for (int i = ty; i < 32; i += 8)
    dst[(size_t)(n0 + i) * K + (k0 + tx)] = f2bf(tile[tx][i]);
}

// ---------- batched bf16 GEMM, C = A @ B^T (+adds), m97 structure ----------
// A: [Z][M][K] bf16, B: [Z][N][K] bf16, C: [Z][M][N] f32 or bf16 (BF16OUT)
// tile 128x128, BK=32, 4 waves (2x2 of 64x64), 16x16x32 MFMA
// XCD-bijective tile swizzle (T1): XCD k gets a contiguous tile chunk;
// within a chunk, n-block is fastest => A-slab L1-reuse, all B-panels of a
// z-slice (4 MB) stay L2-resident. Requires total_tiles % 8 == 0 (2304/288 ok).
template <bool BF16OUT>
__global__ __launch_bounds__(256) void gemm_bt(
    const unsigned short* __restrict__ A, const unsigned short* __restrict__ B,
    void* __restrict__ C, const unsigned short* __restrict__ add0,  // [M][N] bf16 or null
    const float* __restrict__ add1, const float* __restrict__ add2, // [N] or null
    int M, int N, int K) {
  __shared__ unsigned short As[128 * 32];
  __shared__ unsigned short Bs[128 * 32];
  const int tid = threadIdx.x;
  const int w = tid >> 6, l = tid & 63;

  const int gx = gridDim.x, gy = gridDim.y;
  const int lin = blockIdx.x + gx * (blockIdx.y + gy * blockIdx.z);
  const int total = gx * gy * gridDim.z;
  int tile = lin;
  if ((total & 7) == 0) tile = (lin & 7) * (total >> 3) + (lin >> 3);
  const int z  = tile / (gx * gy);
  const int rm = tile - z * (gx * gy);
  const int bx = rm / gy;          // m-block (slow)
  const int by = rm - bx * gy;     // n-block (fast)

  const int m0 = bx * 128, n0 = by * 128;
  const unsigned short* Ab = A + (size_t)z * M * K + (size_t)m0 * K;
  const unsigned short* Bb = B + (size_t)z * N * K + (size_t)n0 * K;
  const size_t coff = (size_t)z * M * N;

  // staging: per wave 64 lanes x 16B; inst 0 covers rows [0,64), inst 1 rows [64,128)
  const int r0 = w * 16 + (l >> 2);       // source row for inst 0 (wave w: rows w*16..w*16+15)
  const int kk = (l & 3) * 8;             // k-element offset within BK tile
  unsigned short* lA = As + w * 512;      // wave-uniform LDS base (w*1024 bytes)
  unsigned short* lB = Bs + w * 512;

  const int wm = (w >> 1) * 64, wn = (w & 1) * 64;
  const int fr = l & 15;                  // fragment row/col
  const int fk = (l >> 4) * 8;            // fragment k offset

  f32x4 acc[4][4];
  #pragma unroll
  for (int a = 0; a < 4; ++a)
    #pragma unroll
    for (int b = 0; b < 4; ++b) acc[a][b] = f32x4{0.f, 0.f, 0.f, 0.f};

  for (int k0 = 0; k0 < K; k0 += 32) {
    const unsigned short* gA = Ab + (size_t)r0 * K + k0 + kk;
    const unsigned short* gB = Bb + (size_t)r0 * K + k0 + kk;
    gld_lds16(gA, lA);
    gld_lds16(gA + (size_t)64 * K, lA + 2048);
    gld_lds16(gB, lB);
    gld_lds16(gB + (size_t)64 * K, lB + 2048);
    __syncthreads();   // compiler drains vmcnt before s_barrier -> LDS tiles ready

    bf16x8 af[4], bg[4];
    #pragma unroll
    for (int mi = 0; mi < 4; ++mi)
      af[mi] = *reinterpret_cast<const bf16x8*>(&As[(wm + mi * 16 + fr) * 32 + fk]);
    #pragma unroll
    for (int ni = 0; ni < 4; ++ni)
      bg[ni] = *reinterpret_cast<const bf16x8*>(&Bs[(wn + ni * 16 + fr) * 32 + fk]);
    #pragma unroll
    for (int mi = 0; mi < 4; ++mi)
      #pragma unroll
      for (int ni = 0; ni < 4; ++ni)
        acc[mi][ni] = __builtin_amdgcn_mfma_f32_16x16x32_bf16(af[mi], bg[ni], acc[mi][ni], 0, 0, 0);
    __syncthreads();
  }

  // epilogue: C/D mapping col = lane&15, row = (lane>>4)*4 + reg   [m89/m91 verified]
  const int er = (l >> 4) * 4;
  #pragma unroll
  for (int mi = 0; mi < 4; ++mi) {
    #pragma unroll
    for (int ni = 0; ni < 4; ++ni) {
      #pragma unroll
      for (int jj = 0; jj < 4; ++jj) {
        const int r = m0 + wm + mi * 16 + er + jj;
        const int c = n0 + wn + ni * 16 + fr;
        float v = acc[mi][ni][jj];
        if constexpr (BF16OUT) {
          ((unsigned short*)C)[coff + (size_t)r * N + c] = f2bf(v);
        } else {
          if (add0) v += bf2f(add0[(size_t)r * N + c]);
          if (add1) v += add1[c];
          if (add2) v += add2[c];
          ((float*)C)[coff + (size_t)r * N + c] = v;
        }
      }
    }
  }
}

// ---------- attention fuse: q=vall[0], kv=vall[1..6] -> fuse (bf16) ----------
// one block (256 thr) per (b,s); each wave handles 2 heads; lane covers 2 of 128 dims
__global__ __launch_bounds__(256) void attn_kernel(const unsigned short* __restrict__ vall,
                                                   unsigned short* __restrict__ fuse) {
  const int bs = blockIdx.x;
  __shared__ float kv[7 * CT];
  const int tid = threadIdx.x;
  // 7*CT = 7168 bf16 -> 1792 ushort4 loads, widen to f32 in LDS
  for (int i4 = tid; i4 < 1792; i4 += 256) {
    const int ll = i4 >> 8, c4 = i4 & 255;
    const ushort4 u = reinterpret_cast<const ushort4*>(
        vall + ((size_t)ll * BS + bs) * CT)[c4];
    float4 f;
    f.x = bf2f(u.x); f.y = bf2f(u.y); f.z = bf2f(u.z); f.w = bf2f(u.w);
    reinterpret_cast<float4*>(kv)[ll * 256 + c4] = f;
  }
  __syncthreads();
  const int w = tid >> 6, l = tid & 63;
  #pragma unroll
  for (int hh = 0; hh < 2; ++hh) {
    const int h = w * 2 + hh;
    const float* qp = &kv[h * 128];
    const float q0 = qp[l * 2] * SCALE, q1 = qp[l * 2 + 1] * SCALE;
    float lg[6];
    #pragma unroll
    for (int j = 0; j < 6; ++j) {
      const float* kp = &kv[(j + 1) * CT + h * 128];
      float p = q0 * kp[l * 2] + q1 * kp[l * 2 + 1];
      #pragma unroll
      for (int o = 32; o; o >>= 1) p += __shfl_xor(p, o);
      lg[j] = p;
    }
    float m = lg[0];
    #pragma unroll
    for (int j = 1; j < 6; ++j) m = fmaxf(m, lg[j]);
    float e[6], sum = 0.f;
    #pragma unroll
    for (int j = 0; j < 6; ++j) { e[j] = expf(lg[j] - m); sum += e[j]; }
    const float inv = 1.f / sum;
    float f0 = 0.f, f1 = 0.f;
    #pragma unroll
    for (int j = 0; j < 6; ++j) {
      const float* kp = &kv[(j + 1) * CT + h * 128];
      const float a = e[j] * inv;
      f0 += a * kp[l * 2];
      f1 += a * kp[l * 2 + 1];
    }
    const unsigned int pk = (unsigned int)f2bf(f0) | ((unsigned int)f2bf(f1) << 16);
    reinterpret_cast<unsigned int*>(fuse + (size_t)bs * CT + (size_t)h * 128)[l] = pk;
  }
}

// ---------- cosine per-row (deterministic partials, no atomics) ----------
__global__ __launch_bounds__(256) void cos_kernel(const float* __restrict__ vf,
                                                  const float* __restrict__ teacher,
                                                  float* __restrict__ cosv) {
  const int bs = blockIdx.x;
  const int tid = threadIdx.x;
  const float4 x = ((const float4*)(vf + (size_t)bs * CT))[tid];
  const float4 y = ((const float4*)(teacher + (size_t)bs * CT))[tid];
  float d = x.x * y.x + x.y * y.y + x.z * y.z + x.w * y.w;
  float n1 = x.x * x.x + x.y * x.y + x.z * x.z + x.w * x.w;
  float n2 = y.x * y.x + y.y * y.y + y.z * y.z + y.w * y.w;
  #pragma unroll
  for (int o = 32; o; o >>= 1) {
    d += __shfl_xor(d, o); n1 += __shfl_xor(n1, o); n2 += __shfl_xor(n2, o);
  }
  __shared__ float r3[12];
  const int w = tid >> 6, l = tid & 63;
  if (l == 0) { r3[w] = d; r3[4 + w] = n1; r3[8 + w] = n2; }
  __syncthreads();
  if (tid == 0) {
    d = r3[0] + r3[1] + r3[2] + r3[3];
    n1 = r3[4] + r3[5] + r3[6] + r3[7];
    n2 = r3[8] + r3[9] + r3[10] + r3[11];
    cosv[bs] = d / (fmaxf(sqrtf(n1), COS_EPS) * fmaxf(sqrtf(n2), COS_EPS));
  }
}

// single block: out = 1 - mean(cosv)
__global__ __launch_bounds__(256) void finish_kernel(const float* __restrict__ cosv,
                                                     float* __restrict__ out) {
  const int tid = threadIdx.x;
  float s = 0.f;
  for (int i = tid; i < BS; i += 256) s += cosv[i];
  #pragma unroll
  for (int o = 32; o; o >>= 1) s += __shfl_xor(s, o);
  __shared__ float red[4];
  const int w = tid >> 6, l = tid & 63;
  if (l == 0) red[w] = s;
  __syncthreads();
  if (tid == 0) out[0] = 1.f - (red[0] + red[1] + red[2] + red[3]) * (1.f / (float)BS);
}

// ---------- launch ----------
extern "C" void kernel_launch(void* const* d_in, const int* in_sizes, int n_in,
                              void* d_out, int out_size, void* d_ws, size_t ws_size,
                              hipStream_t stream) {
  const float* features = (const float*)d_in[0];
  const float* teacher  = (const float*)d_in[1];
  const float* ln_scale = (const float*)d_in[2];
  const float* ln_bias  = (const float*)d_in[3];
  const float* w_norm   = (const float*)d_in[4];
  const float* w_in     = (const float*)d_in[5];
  const float* b_in     = (const float*)d_in[6];
  const float* w_out    = (const float*)d_in[7];
  const float* b_out    = (const float*)d_in[8];
  float* out = (float*)d_out;

  char* p = (char*)d_ws;
  unsigned short* xa  = (unsigned short*)p; p += (size_t)NZ * BS * D * 2;   // A  [8][4608][2048] bf16
  unsigned short* wT  = (unsigned short*)p; p += (size_t)NZ * CT * D * 2;   // B^T [8][1024][2048] bf16
  unsigned short* wOT = (unsigned short*)p; p += (size_t)CT * CT * 2;       // w_out^T bf16
  unsigned short* vall= (unsigned short*)p; p += (size_t)NZ * BS * CT * 2;  // [8][4608][1024] bf16
  unsigned short* fuse= (unsigned short*)p; p += (size_t)BS * CT * 2;       // bf16
  float* vf           = (float*)p;          p += (size_t)BS * CT * 4;       // f32
  float* cosv         = (float*)p;          p += (size_t)BS * 4;

  prep_kernel<<<LN_BLOCKS + WP_BLOCKS, 256, 0, stream>>>(
      features, ln_scale, ln_bias, w_norm, w_in, w_out, xa, wT, wOT);
  gemm_bt<true><<<dim3(BS / 128, CT / 128, NZ), 256, 0, stream>>>(
      xa, wT, vall, nullptr, nullptr, nullptr, BS, CT, D);
  attn_kernel<<<BS, 256, 0, stream>>>(vall, fuse);
  gemm_bt<false><<<dim3(BS / 128, CT / 128, 1), 256, 0, stream>>>(
      fuse, wOT, vf, vall + (size_t)7 * BS * CT, b_in, b_out, BS, CT, CT);
  cos_kernel<<<BS, 256, 0, stream>>>(vf, teacher, cosv);
  finish_kernel<<<1, 256, 0, stream>>>(cosv, out);
}